// Round 5
// baseline (167.950 us; speedup 1.0000x reference)
//
#include <hip/hip_runtime.h>
#include <hip/hip_bf16.h>

#define NPOS   100
#define BATCH  1024
#define DIN    384
#define DOUT   384
#define XROW   (NPOS * DIN)      // 38400 floats, batch-dim stride of x and out
#define WSLICE (DIN * DOUT)

#define BM 64                    // batch rows per block
#define BN 384                   // full d_out per block -> x read exactly once
#define BK 32
#define NK (DIN / BK)            // 12 K-steps
#define PA 40                    // A pitch (shorts): 80B rows, 16B-aligned b128 reads
#define PB 36                    // B^T pitch (shorts): 72B rows, 8B-aligned b64 reads
#define NMT (BATCH / BM)         // 16 mt-blocks per slice

typedef __attribute__((ext_vector_type(8))) short bf16x8;
typedef __attribute__((ext_vector_type(16))) float f32x16;

__device__ __forceinline__ unsigned f2bfu(float f) {
  return (unsigned)__builtin_bit_cast(unsigned short, __float2bfloat16(f));
}
__device__ __forceinline__ unsigned pack2(float a, float b) {
  return f2bfu(a) | (f2bfu(b) << 16);
}
__device__ __forceinline__ unsigned ext16(unsigned u, int h) {
  return h ? (u >> 16) : (u & 0xffffu);
}

// ds ops visible, vmcnt NOT drained (global prefetch survives the barrier)
__device__ __forceinline__ void barrier_nodrain() {
  asm volatile("s_waitcnt lgkmcnt(0)" ::: "memory");
  __builtin_amdgcn_s_barrier();
}

// B^T frag read from 8B-aligned rows: two ds_read_b64 (no b128 on 72B pitch)
__device__ __forceinline__ bf16x8 ldB8(const short* p) {
  uint2 lo = *reinterpret_cast<const uint2*>(p);
  uint2 hi = *reinterpret_cast<const uint2*>(p + 4);
  union { unsigned u[4]; bf16x8 v; } r;
  r.u[0] = lo.x; r.u[1] = lo.y; r.u[2] = hi.x; r.u[3] = hi.y;
  return r.v;
}

__global__ __launch_bounds__(512, 4) void nlinear_kernel(
    const float* __restrict__ x, const float* __restrict__ w,
    const float* __restrict__ bias, float* __restrict__ out)
{
  __shared__ short lA[2][BM * PA];   // [b-row][k]  (10.0 KiB)
  __shared__ short lB[2][BN * PB];   // [o-row][k]  (54.0 KiB) -> 64 KiB total

  const int tid  = threadIdx.x;
  const int lane = tid & 63;
  const int wave = tid >> 6;            // 8 waves: 2m x 4n
  const int wm   = wave >> 2;           // 0..1  (32 rows each)
  const int wn   = wave & 3;            // 0..3  (96 cols each)
  const int l31  = lane & 31;
  const int kHi  = (lane >> 5) * 8;

  // XCD-aware bijective swizzle: 1600 = 8 * 200; same-slice blocks adjacent on one XCD
  const int bid   = blockIdx.x;
  const int swz   = (bid & 7) * 200 + (bid >> 3);
  const int slice = swz >> 4;           // 0..99
  const int mt    = swz & 15;           // 0..15

  const float* xbase = x    + (size_t)mt * BM * XROW + (size_t)slice * DIN;
  const float* wbase = w    + (size_t)slice * WSLICE;
  const float* bbase = bias + (size_t)slice * DOUT;
  float*       obase = out  + (size_t)mt * BM * XROW + (size_t)slice * DOUT;

  // A staging: 1 float4/thread; lanes 0..7 = 128B run of one row
  const int a_c4  = tid & 7;
  const int a_row = tid >> 3;           // 0..63
  // B staging: lane varies k (8 rows x 128B per inst); o-chunk from tid>>3
  const int b_kq  = tid & 7;            // k-block 0..7
  const int b_o4  = tid >> 3;           // 0..63  -> o cols 0..255
  const int b_o42 = 64 + (tid >> 3);    // 64..95 -> o cols 256..383 (tid<256)
  const bool p2   = (tid < 256);        // waves 0-3 (wave-uniform)

  unsigned au[2];        // A as packed bf16 pairs (converted at load)
  unsigned bu1[4][2];    // B pass1: [dk][half]
  unsigned bu2[4][2];    // B pass2

  auto G2R = [&](int k0) {
    {
      const float4 v = *reinterpret_cast<const float4*>(
          xbase + (size_t)a_row * XROW + k0 + a_c4 * 4);
      au[0] = pack2(v.x, v.y);
      au[1] = pack2(v.z, v.w);
    }
#pragma unroll
    for (int dk = 0; dk < 4; ++dk) {
      const float4 v = *reinterpret_cast<const float4*>(
          wbase + (size_t)(k0 + b_kq * 4 + dk) * DOUT + b_o4 * 4);
      bu1[dk][0] = pack2(v.x, v.y);
      bu1[dk][1] = pack2(v.z, v.w);
    }
    if (p2) {
#pragma unroll
      for (int dk = 0; dk < 4; ++dk) {
        const float4 v = *reinterpret_cast<const float4*>(
            wbase + (size_t)(k0 + b_kq * 4 + dk) * DOUT + b_o42 * 4);
        bu2[dk][0] = pack2(v.x, v.y);
        bu2[dk][1] = pack2(v.z, v.w);
      }
    }
  };

  auto R2L = [&](int buf) {
    *reinterpret_cast<uint2*>(&lA[buf][a_row * PA + a_c4 * 4]) =
        uint2{au[0], au[1]};
    // B^T: row o gets k-chunk b_kq as uint2 (register 4x4 transpose via extracts)
#pragma unroll
    for (int c = 0; c < 4; ++c) {
      uint2 t;
      t.x = ext16(bu1[0][c >> 1], c & 1) | (ext16(bu1[1][c >> 1], c & 1) << 16);
      t.y = ext16(bu1[2][c >> 1], c & 1) | (ext16(bu1[3][c >> 1], c & 1) << 16);
      *reinterpret_cast<uint2*>(&lB[buf][(b_o4 * 4 + c) * PB + b_kq * 4]) = t;
    }
    if (p2) {
#pragma unroll
      for (int c = 0; c < 4; ++c) {
        uint2 t;
        t.x = ext16(bu2[0][c >> 1], c & 1) | (ext16(bu2[1][c >> 1], c & 1) << 16);
        t.y = ext16(bu2[2][c >> 1], c & 1) | (ext16(bu2[3][c >> 1], c & 1) << 16);
        *reinterpret_cast<uint2*>(&lB[buf][(b_o42 * 4 + c) * PB + b_kq * 4]) = t;
      }
    }
  };

  f32x16 acc[3];
#pragma unroll
  for (int n = 0; n < 3; ++n)
#pragma unroll
    for (int r = 0; r < 16; ++r)
      acc[n][r] = 0.f;

  G2R(0);
  R2L(0);
  barrier_nodrain();
  G2R(BK);

  auto STEP = [&](int ks, int cb) {
    if (ks + 1 < NK) R2L(cb ^ 1);
    if (ks + 2 < NK) G2R((ks + 2) * BK);
    bf16x8 af[2];      // [kk]
    bf16x8 bf[2][3];   // [kk][n]
#pragma unroll
    for (int kk = 0; kk < 2; ++kk)
      af[kk] = *reinterpret_cast<const bf16x8*>(
          &lA[cb][(wm * 32 + l31) * PA + kk * 16 + kHi]);
#pragma unroll
    for (int kk = 0; kk < 2; ++kk)
#pragma unroll
      for (int n = 0; n < 3; ++n)
        bf[kk][n] = ldB8(&lB[cb][(wn * 96 + n * 32 + l31) * PB + kk * 16 + kHi]);
#pragma unroll
    for (int kk = 0; kk < 2; ++kk)
#pragma unroll
      for (int n = 0; n < 3; ++n)
        acc[n] = __builtin_amdgcn_mfma_f32_32x32x16_bf16(
            af[kk], bf[kk][n], acc[n], 0, 0, 0);
    barrier_nodrain();
  };

#pragma unroll
  for (int ks = 0; ks < NK; ks += 2) {
    STEP(ks, 0);
    STEP(ks + 1, 1);
  }

  // Epilogue. 32x32 D frag: col = lane&31, row = (r&3) + 8*(r>>2) + 4*(lane>>5)
  float bv[3];
#pragma unroll
  for (int n = 0; n < 3; ++n) bv[n] = bbase[wn * 96 + n * 32 + l31];

  const int rbase = wm * 32 + ((lane >> 5) << 2);
#pragma unroll
  for (int n = 0; n < 3; ++n) {
    const int c = wn * 96 + n * 32 + l31;
#pragma unroll
    for (int r = 0; r < 16; ++r) {
      const int row = rbase + (r & 3) + 8 * (r >> 2);
      obase[(size_t)row * XROW + c] = acc[n][r] + bv[n];
    }
  }
}

extern "C" void kernel_launch(void* const* d_in, const int* in_sizes, int n_in,
                              void* d_out, int out_size, void* d_ws, size_t ws_size,
                              hipStream_t stream) {
  const float* x  = (const float*)d_in[0];
  const float* w  = (const float*)d_in[1];
  const float* b  = (const float*)d_in[2];
  float* out      = (float*)d_out;
  const int grid  = NPOS * NMT;  // 1600
  nlinear_kernel<<<grid, 512, 0, stream>>>(x, w, b, out);
}

// Round 6
// 123.372 us; speedup vs baseline: 1.3613x; 1.3613x over previous
//
#include <hip/hip_runtime.h>
#include <hip/hip_bf16.h>

#define NPOS   100
#define BATCH  1024
#define DIN    384
#define DOUT   384
#define XROW   (NPOS * DIN)      // 38400 floats, batch-dim stride of x and out
#define WSLICE (DIN * DOUT)

#define BM 128
#define BN 128
#define BK 32
#define NK (DIN / BK)            // 12 K-steps
#define PA 40                    // A pitch (shorts): 80B rows
#define PB 40                    // B^T pitch (shorts): 80B rows, b128-aligned granules

typedef __attribute__((ext_vector_type(8))) short bf16x8;
typedef __attribute__((ext_vector_type(16))) float f32x16;

__device__ __forceinline__ unsigned f2bfu(float f) {
  return (unsigned)__builtin_bit_cast(unsigned short, __float2bfloat16(f));
}
__device__ __forceinline__ unsigned pack2(float a, float b) {
  return f2bfu(a) | (f2bfu(b) << 16);
}
__device__ __forceinline__ unsigned ext16(unsigned u, int h) {
  return h ? (u >> 16) : (u & 0xffffu);
}

// ds ops visible, vmcnt NOT drained (global prefetch survives the barrier)
__device__ __forceinline__ void barrier_nodrain() {
  asm volatile("s_waitcnt lgkmcnt(0)" ::: "memory");
  __builtin_amdgcn_s_barrier();
}

__global__ __launch_bounds__(256, 4) void nlinear_kernel(
    const float* __restrict__ x, const float* __restrict__ w,
    const float* __restrict__ bias, float* __restrict__ out)
{
  __shared__ short lA[2][BM * PA];   // [b-row][k]  10.0 KiB x2
  __shared__ short lB[2][BN * PB];   // [o-row][k]  10.0 KiB x2  -> 40 KiB total

  const int tid  = threadIdx.x;
  const int lane = tid & 63;
  const int wave = tid >> 6;            // 4 waves: 2m x 2n
  const int wm   = wave >> 1;
  const int wn   = wave & 1;
  const int l31  = lane & 31;
  const int kHi  = (lane >> 5) * 8;     // 8-short k sub-offset
  const int gHalf = lane >> 5;          // granule half selector
  const int xr   = (l31 >> 3) & 3;      // k-granule XOR key (lane-constant)

  // XCD-aware bijective swizzle: 2400 blocks = 8 * 300
  const int bid   = blockIdx.x;
  const int swz   = (bid & 7) * 300 + (bid >> 3);
  const int slice = swz / 24;
  const int rem   = swz - slice * 24;
  const int mt    = rem / 3;
  const int nt    = rem - mt * 3;

  const float* xbase = x    + (size_t)mt * BM * XROW + (size_t)slice * DIN;
  const float* wbase = w    + (size_t)slice * WSLICE + nt * BN;
  const float* bbase = bias + (size_t)slice * DOUT   + nt * BN;
  float*       obase = out  + (size_t)mt * BM * XROW + (size_t)slice * DOUT + nt * BN;

  // A staging: 4 float4/thread (8 lines/inst), same as R3
  const int a_c4   = tid & 7;
  const int a_row0 = tid >> 3;          // 0..31, +32i
  // B staging: lane varies k-block (8 rows x 128B per inst), o-quad = tid>>3
  const int b_kb   = tid & 7;           // k-block: k = kb*4+dk
  const int b_oq   = tid >> 3;          // 0..31 -> o cols oq*4..+3
  const int b_gw   = (b_kb >> 1) ^ ((b_oq >> 1) & 3);  // swizzled write granule
  const int b_h    = b_kb & 1;

  unsigned au[4][2];    // A packed bf16 (converted at load)
  unsigned bu[4][2];    // B: [dk][half], o-cols oq*4..+3 of k-row kb*4+dk

  auto G2R = [&](int k0) {
#pragma unroll
    for (int i = 0; i < 4; ++i) {
      const float4 v = *reinterpret_cast<const float4*>(
          xbase + (size_t)(a_row0 + 32 * i) * XROW + k0 + a_c4 * 4);
      au[i][0] = pack2(v.x, v.y);
      au[i][1] = pack2(v.z, v.w);
    }
#pragma unroll
    for (int dk = 0; dk < 4; ++dk) {
      const float4 v = *reinterpret_cast<const float4*>(
          wbase + (size_t)(k0 + b_kb * 4 + dk) * DOUT + b_oq * 4);
      bu[dk][0] = pack2(v.x, v.y);
      bu[dk][1] = pack2(v.z, v.w);
    }
  };

  auto R2L = [&](int buf) {
#pragma unroll
    for (int i = 0; i < 4; ++i) {
      *reinterpret_cast<uint2*>(&lA[buf][(a_row0 + 32 * i) * PA + a_c4 * 4]) =
          uint2{au[i][0], au[i][1]};
    }
    // B^T: row o = oq*4+c gets k-shorts kb*4..+3 as uint2 at swizzled granule
#pragma unroll
    for (int c = 0; c < 4; ++c) {
      uint2 t;
      t.x = ext16(bu[0][c >> 1], c & 1) | (ext16(bu[1][c >> 1], c & 1) << 16);
      t.y = ext16(bu[2][c >> 1], c & 1) | (ext16(bu[3][c >> 1], c & 1) << 16);
      *reinterpret_cast<uint2*>(
          &lB[buf][(b_oq * 4 + c) * PB + b_gw * 8 + b_h * 4]) = t;
    }
  };

  f32x16 acc[2][2];
#pragma unroll
  for (int m = 0; m < 2; ++m)
#pragma unroll
    for (int n = 0; n < 2; ++n)
#pragma unroll
      for (int r = 0; r < 16; ++r)
        acc[m][n][r] = 0.f;

  G2R(0);
  R2L(0);
  barrier_nodrain();
  G2R(BK);

  auto STEP = [&](int ks, int cb) {
    if (ks + 1 < NK) R2L(cb ^ 1);
    if (ks + 2 < NK) G2R((ks + 2) * BK);
    bf16x8 af[2][2];   // [kk][m]
    bf16x8 bf[2][2];   // [kk][n]
#pragma unroll
    for (int kk = 0; kk < 2; ++kk)
#pragma unroll
      for (int m = 0; m < 2; ++m)
        af[kk][m] = *reinterpret_cast<const bf16x8*>(
            &lA[cb][(wm * 64 + m * 32 + l31) * PA + kk * 16 + kHi]);
#pragma unroll
    for (int kk = 0; kk < 2; ++kk)
#pragma unroll
      for (int n = 0; n < 2; ++n) {
        const int g = (kk * 2 + gHalf) ^ xr;   // swizzled read granule
        bf[kk][n] = *reinterpret_cast<const bf16x8*>(
            &lB[cb][(wn * 64 + n * 32 + l31) * PB + g * 8]);
      }
#pragma unroll
    for (int kk = 0; kk < 2; ++kk)
#pragma unroll
      for (int m = 0; m < 2; ++m)
#pragma unroll
        for (int n = 0; n < 2; ++n)
          acc[m][n] = __builtin_amdgcn_mfma_f32_32x32x16_bf16(
              af[kk][m], bf[kk][n], acc[m][n], 0, 0, 0);
    barrier_nodrain();
  };

#pragma unroll
  for (int ks = 0; ks < NK; ks += 2) {
    STEP(ks, 0);
    STEP(ks + 1, 1);
  }

  // Epilogue. 32x32 D frag: col = lane&31, row = (r&3) + 8*(r>>2) + 4*(lane>>5)
  float bv[2];
#pragma unroll
  for (int n = 0; n < 2; ++n) bv[n] = bbase[wn * 64 + n * 32 + l31];

  const int rbase = wm * 64 + ((lane >> 5) << 2);
#pragma unroll
  for (int m = 0; m < 2; ++m) {
#pragma unroll
    for (int n = 0; n < 2; ++n) {
      const int c = wn * 64 + n * 32 + l31;
#pragma unroll
      for (int r = 0; r < 16; ++r) {
        const int row = rbase + m * 32 + (r & 3) + 8 * (r >> 2);
        obase[(size_t)row * XROW + c] = acc[m][n][r] + bv[n];
      }
    }
  }
}

extern "C" void kernel_launch(void* const* d_in, const int* in_sizes, int n_in,
                              void* d_out, int out_size, void* d_ws, size_t ws_size,
                              hipStream_t stream) {
  const float* x  = (const float*)d_in[0];
  const float* w  = (const float*)d_in[1];
  const float* b  = (const float*)d_in[2];
  float* out      = (float*)d_out;
  const int grid  = NPOS * (BATCH / BM) * (DOUT / BN);  // 2400
  nlinear_kernel<<<grid, 256, 0, stream>>>(x, w, b, out);
}